// Round 1
// 266.534 us; speedup vs baseline: 1.0737x; 1.0737x over previous
//
#include <hip/hip_runtime.h>
#include <hip/hip_bf16.h>
#include <math.h>

#define D_MODEL 1024
#define NHEADS  16
#define HDIM    64
#define BATCH   4
#define SEQ     2048

typedef __attribute__((ext_vector_type(8))) short bf16x8;
typedef __attribute__((ext_vector_type(4))) float f32x4;

#if __has_builtin(__builtin_amdgcn_exp2f)
#define EXP2(x) __builtin_amdgcn_exp2f(x)
#else
#define EXP2(x) exp2f(x)
#endif

__device__ __forceinline__ unsigned short f2bf(float f) {
  union { float f; unsigned u; } v; v.f = f;
  unsigned r = v.u + 0x7FFFu + ((v.u >> 16) & 1u);   // RNE
  return (unsigned short)(r >> 16);
}

__device__ __forceinline__ void load_lds16(const unsigned short* g, unsigned short* l) {
  __builtin_amdgcn_global_load_lds(
      (const __attribute__((address_space(1))) unsigned int*)g,
      (__attribute__((address_space(3))) unsigned int*)l, 16, 0, 0);
}

// ---- pre-pass: fp32 -> bf16 cast (x) ----
__global__ __launch_bounds__(256) void cast_kernel(
    const float* __restrict__ in, unsigned short* __restrict__ out)
{
  const int idx = (blockIdx.x * 256 + threadIdx.x) * 8;
  float4 a = *(const float4*)&in[idx];
  float4 b = *(const float4*)&in[idx + 4];
  alignas(16) unsigned short t[8] = {
    f2bf(a.x), f2bf(a.y), f2bf(a.z), f2bf(a.w),
    f2bf(b.x), f2bf(b.y), f2bf(b.z), f2bf(b.w)};
  *(uint4*)&out[idx] = *(uint4*)t;
}

// ---- pre-pass: W [1024][N] fp32 -> WT [N][1024] bf16 ----
__global__ __launch_bounds__(256) void transpose_cast(
    const float* __restrict__ W, unsigned short* __restrict__ WT, int N)
{
  __shared__ float t[64][65];
  const int k0 = blockIdx.y * 64, n0 = blockIdx.x * 64;
  const int tid = threadIdx.x;
  const int r = tid >> 2, c0 = (tid & 3) * 16;
  #pragma unroll
  for (int i = 0; i < 16; i += 4) {
    float4 f = *(const float4*)&W[(size_t)(k0 + r) * N + n0 + c0 + i];
    t[r][c0+i] = f.x; t[r][c0+i+1] = f.y; t[r][c0+i+2] = f.z; t[r][c0+i+3] = f.w;
  }
  __syncthreads();
  #pragma unroll
  for (int i = 0; i < 16; i += 4) {
    alignas(8) unsigned short s[4] = {
      f2bf(t[c0+i][r]), f2bf(t[c0+i+1][r]), f2bf(t[c0+i+2][r]), f2bf(t[c0+i+3][r])};
    *(uint2*)&WT[(size_t)(n0 + r) * 1024 + k0 + c0 + i] = *(uint2*)s;
  }
}

#define BARRIER __builtin_amdgcn_s_barrier()
#define FENCE   asm volatile("" ::: "memory")
#define LGKM0   do { asm volatile("s_waitcnt lgkmcnt(0)" ::: "memory"); \
                     __builtin_amdgcn_sched_barrier(0); } while (0)

// ---- 128x256-tile fine-phased GEMM: C[M x N] = A[M x 1024] @ BT[N x 1024]^T + bias
// 8 waves (512 thr), per-wave 64x64 output. 2-buffer LDS (96 KiB), counted
// vmcnt(6) pipeline (never drains in main loop), T2 XOR-swizzle on stage
// source + ds_read, T5 setprio around MFMA clusters.
template<int MODE>
__global__ __launch_bounds__(512, 2) void gemm8p(
    const unsigned short* __restrict__ A,
    const unsigned short* __restrict__ Bt,
    const float* __restrict__ bias,
    unsigned short* __restrict__ Qb, unsigned short* __restrict__ Kb,
    unsigned short* __restrict__ Vb, float* __restrict__ Out)
{
  constexpr int N  = (MODE == 0) ? 3 * D_MODEL : D_MODEL;
  constexpr int NT = D_MODEL / 64;                 // 16 K-tiles
  const int bn = blockIdx.x * 256;
  const int bm = blockIdx.y * 128;
  const int tid  = threadIdx.x;
  const int lane = tid & 63;
  const int w    = tid >> 6;
  const int quad = lane >> 4;
  const int l16  = lane & 15;
  const int wr = w >> 2, wc = w & 3;

  // A: [2][128][64] @ 0 (8192 shorts/buf), B: [2][256][64] @ 16384
  __shared__ __align__(16) unsigned short lds[49152];   // 96 KiB

  // Staging: linear LDS dest (global_load_lds requirement), swizzle applied
  // to the per-lane GLOBAL source column (rule 21: both-sides-or-neither).
  const int srow = lane >> 3;                       // row within 8-row wave slice
  const int scol = ((lane & 7) ^ srow) * 8;         // pre-swizzled 16B slot
  const unsigned short* __restrict__ Ag = A  + (size_t)(bm + w*8 + srow) * D_MODEL + scol;
  const unsigned short* __restrict__ Bg = Bt + (size_t)(bn + w*8 + srow) * D_MODEL + scol;
  const int xs = (l16 & 7) * 8;                     // read-side XOR (elems)

  f32x4 acc[4][4] = {};

  auto stageA = [&](int buf, int t2) {              // 2 x 8KB chunks
    unsigned short* d = &lds[buf*8192 + w*512];
    const unsigned short* g = Ag + t2*64;
    load_lds16(g,                     d);
    load_lds16(g + (size_t)64*D_MODEL, d + 4096);
  };
  auto stageB = [&](int buf, int t2) {              // 4 x 8KB chunks
    unsigned short* d = &lds[16384 + buf*16384 + w*512];
    const unsigned short* g = Bg + t2*64;
    #pragma unroll
    for (int c = 0; c < 4; c++)
      load_lds16(g + (size_t)c*64*D_MODEL, d + c*4096);
  };
  auto rdA = [&](int buf, int mi, int kk) {
    return *(const bf16x8*)&lds[buf*8192 +
        (wr*64 + mi*16 + l16)*64 + (((kk*4 + quad)*8) ^ xs)];
  };
  auto rdB = [&](int buf, int ni, int kk) {
    return *(const bf16x8*)&lds[16384 + buf*16384 +
        (wc*64 + ni*16 + l16)*64 + (((kk*4 + quad)*8) ^ xs)];
  };

  // ---- prologue: stage tiles 0 and 1, wait tile 0 only (6 newest in flight)
  stageB(0, 0); stageA(0, 0);
  stageB(1, 1); stageA(1, 1);
  asm volatile("s_waitcnt vmcnt(6)" ::: "memory");
  BARRIER;
  FENCE;

  #pragma unroll 2
  for (int t = 0; t < NT; ++t) {
    const int cur  = t & 1;
    const bool pre = (t + 2 < NT);
    bf16x8 a0[2][2], a1[2][2], b0[2][2], b1[2][2];

    // ---- phase 0: read A(mi0-1)+B(ni0-1), MFMA quadrant (mi0-1 x ni0-1) ----
    #pragma unroll
    for (int kk = 0; kk < 2; kk++)
      #pragma unroll
      for (int i = 0; i < 2; i++) { a0[i][kk] = rdA(cur, i, kk); b0[i][kk] = rdB(cur, i, kk); }
    BARRIER; LGKM0;
    __builtin_amdgcn_s_setprio(1);
    #pragma unroll
    for (int kk = 0; kk < 2; kk++)
      #pragma unroll
      for (int mi = 0; mi < 2; mi++)
        #pragma unroll
        for (int ni = 0; ni < 2; ni++)
          acc[mi][ni] = __builtin_amdgcn_mfma_f32_16x16x32_bf16(a0[mi][kk], b0[ni][kk], acc[mi][ni], 0, 0, 0);
    __builtin_amdgcn_s_setprio(0);
    BARRIER;

    // ---- phase 1: read B(ni2-3), MFMA (mi0-1 x ni2-3) ----
    #pragma unroll
    for (int kk = 0; kk < 2; kk++)
      #pragma unroll
      for (int i = 0; i < 2; i++) b1[i][kk] = rdB(cur, 2 + i, kk);
    BARRIER; LGKM0;
    __builtin_amdgcn_s_setprio(1);
    #pragma unroll
    for (int kk = 0; kk < 2; kk++)
      #pragma unroll
      for (int mi = 0; mi < 2; mi++)
        #pragma unroll
        for (int ni = 0; ni < 2; ni++)
          acc[mi][2+ni] = __builtin_amdgcn_mfma_f32_16x16x32_bf16(a0[mi][kk], b1[ni][kk], acc[mi][2+ni], 0, 0, 0);
    __builtin_amdgcn_s_setprio(0);
    BARRIER;
    // all B-reads of buf[cur] retired (each wave's lgkmcnt(0) preceded its
    // MFMAs, which preceded this barrier) -> B region is safe to restage.

    // ---- phase 2: read A(mi2-3); stage B(t+2) into freed B region ----
    #pragma unroll
    for (int kk = 0; kk < 2; kk++)
      #pragma unroll
      for (int i = 0; i < 2; i++) a1[i][kk] = rdA(cur, 2 + i, kk);
    if (pre) stageB(cur, t + 2);
    BARRIER; LGKM0;
    __builtin_amdgcn_s_setprio(1);
    #pragma unroll
    for (int kk = 0; kk < 2; kk++)
      #pragma unroll
      for (int mi = 0; mi < 2; mi++)
        #pragma unroll
        for (int ni = 0; ni < 2; ni++)
          acc[2+mi][ni] = __builtin_amdgcn_mfma_f32_16x16x32_bf16(a1[mi][kk], b0[ni][kk], acc[2+mi][ni], 0, 0, 0);
    __builtin_amdgcn_s_setprio(0);
    BARRIER;
    // all A-reads of buf[cur] retired -> A region safe to restage.

    // ---- phase 3: stage A(t+2); counted vmcnt (tile t+1 landed, t+2 in
    // flight); MFMA (mi2-3 x ni2-3) from registers ----
    if (pre) {
      stageA(cur, t + 2);
      asm volatile("s_waitcnt vmcnt(6)" ::: "memory");
    } else {
      asm volatile("s_waitcnt vmcnt(0)" ::: "memory");
    }
    BARRIER;
    FENCE;   // keep next tile's ds_reads below this barrier
    __builtin_amdgcn_s_setprio(1);
    #pragma unroll
    for (int kk = 0; kk < 2; kk++)
      #pragma unroll
      for (int mi = 0; mi < 2; mi++)
        #pragma unroll
        for (int ni = 0; ni < 2; ni++)
          acc[2+mi][2+ni] = __builtin_amdgcn_mfma_f32_16x16x32_bf16(a1[mi][kk], b1[ni][kk], acc[2+mi][2+ni], 0, 0, 0);
    __builtin_amdgcn_s_setprio(0);
    BARRIER;
  }

  // ---- epilogue (same mapping as before; per-wave tile = 64x64) ----
  const int b   = bm >> 11;
  const int tl0 = (bm & (SEQ - 1));
  #pragma unroll
  for (int ni = 0; ni < 4; ni++) {
    const int n = bn + wc*64 + ni*16 + l16;
    const float bv = bias[n];
    #pragma unroll
    for (int mi = 0; mi < 4; mi++) {
      const int t0 = tl0 + wr*64 + mi*16 + quad*4;
      if (MODE == 0) {
        const int which = n >> 10;
        const int c = n & 1023;
        const int h = c >> 6, hd = c & 63;
        const size_t bhb = ((size_t)(b*NHEADS + h)) * (SEQ*HDIM);
        if (which == 2) {
          alignas(8) unsigned short pk[4];
          #pragma unroll
          for (int r = 0; r < 4; r++) pk[r] = f2bf(acc[mi][ni][r] + bv);
          *(uint2*)&Vb[bhb + (size_t)hd*SEQ + t0] = *(uint2*)pk;
        } else if (which == 0) {
          #pragma unroll
          for (int r = 0; r < 4; r++)
            Qb[bhb + (size_t)(t0 + r)*HDIM + hd] = f2bf((acc[mi][ni][r] + bv) * 0.18033688f);
        } else {
          #pragma unroll
          for (int r = 0; r < 4; r++)
            Kb[bhb + (size_t)(t0 + r)*HDIM + hd] = f2bf(acc[mi][ni][r] + bv);
        }
      } else {
        const int m = bm + wr*64 + mi*16 + quad*4;
        #pragma unroll
        for (int r = 0; r < 4; r++)
          Out[(size_t)(m + r) * N + n] = acc[mi][ni][r] + bv;
      }
    }
  }
}

// Flash attention v8 (unchanged): block-cooperative, m97-style LDS staging.
__global__ __launch_bounds__(256) void attn_kernel(
    const unsigned short* __restrict__ Qb,
    const unsigned short* __restrict__ Kb,
    const unsigned short* __restrict__ Vt,
    unsigned short* __restrict__ Yb)
{
  const int bh   = blockIdx.x;
  const int Gp   = blockIdx.y;
  const int tid  = threadIdx.x;
  const int wave = tid >> 6;
  const int lane = tid & 63;
  const int quad = lane >> 4;
  const int l16  = lane & 15;

  __shared__ __align__(16) unsigned short Ks[64 * 64];      // [key][hd]
  __shared__ __align__(16) unsigned short Vs[64 * 64];      // [hd][key]
  __shared__ __align__(16) unsigned short Pl[8][16][72];    // per-strip P (bf16)

  const unsigned short* __restrict__ qb_ = Qb + (size_t)bh * (SEQ*HDIM);
  const unsigned short* __restrict__ kb_ = Kb + (size_t)bh * (SEQ*HDIM);
  const unsigned short* __restrict__ vb_ = Vt + (size_t)bh * (SEQ*HDIM);
  const int h = bh & (NHEADS - 1);
  const int b = bh >> 4;

  const short ob = (short)0x3F80;    // bf16 1.0
  const bf16x8 ones = {ob,ob,ob,ob,ob,ob,ob,ob};

  const int kst = wave * 1024 + lane * 8;            // K: flat 8KB copy
  const int vrow = wave * 16 + (lane >> 3);          // V: hd row base
  const int vcol = (lane & 7) * 8;

  for (int half = 0; half < 2; half++) {
    const int qt = half ? (15 - Gp) : Gp;
    const int ntiles = 2 * qt + 2;
    const int qs0 = qt * 128 + wave * 32;
    const int myLast = 2 * qt + (wave >> 1);         // last tile this wave needs

    bf16x8 qf[2][2];
    #pragma unroll
    for (int t = 0; t < 2; t++)
      #pragma unroll
      for (int kk = 0; kk < 2; kk++)
        qf[t][kk] = *(const bf16x8*)(qb_ + (qs0 + t*16 + l16)*HDIM + kk*32 + quad*8);

    f32x4 acc[2][4] = {};
    float lrow[2][4] = {};

    for (int it = 0; it < ntiles; it++) {
      const int kb = it * 64;

      #pragma unroll
      for (int j = 0; j < 2; j++)
        load_lds16(kb_ + (size_t)kb*HDIM + kst + j*512, &Ks[wave*1024 + j*512]);
      #pragma unroll
      for (int j = 0; j < 2; j++)
        load_lds16(vb_ + (size_t)(vrow + j*8)*SEQ + kb + vcol, &Vs[(wave*16 + j*8)*64]);
      __syncthreads();

      if (it <= myLast) {
        f32x4 sfr[4] = {}, sfr1[4] = {};
        #pragma unroll
        for (int kk = 0; kk < 2; kk++)
          #pragma unroll
          for (int nf = 0; nf < 4; nf++) {
            const bf16x8 kf = *(const bf16x8*)&Ks[(nf*16 + l16)*64 + kk*32 + quad*8];
            sfr[nf]  = __builtin_amdgcn_mfma_f32_16x16x32_bf16(qf[0][kk], kf, sfr[nf], 0, 0, 0);
            sfr1[nf] = __builtin_amdgcn_mfma_f32_16x16x32_bf16(qf[1][kk], kf, sfr1[nf], 0, 0, 0);
          }

        if (it == myLast) {
          #pragma unroll
          for (int nf = 0; nf < 4; nf++) {
            const int kcol = kb + nf*16 + l16;
            #pragma unroll
            for (int r = 0; r < 4; r++) {
              sfr[nf][r]  = (kcol > qs0 + quad*4 + r)      ? -INFINITY : sfr[nf][r];
              sfr1[nf][r] = (kcol > qs0 + 16 + quad*4 + r) ? -INFINITY : sfr1[nf][r];
            }
          }
        }

        #pragma unroll
        for (int nf = 0; nf < 4; nf++)
          #pragma unroll
          for (int r = 0; r < 4; r++) {
            Pl[wave*2 + 0][quad*4 + r][nf*16 + l16] = f2bf(EXP2(sfr[nf][r]));
            Pl[wave*2 + 1][quad*4 + r][nf*16 + l16] = f2bf(EXP2(sfr1[nf][r]));
          }

        #pragma unroll
        for (int t = 0; t < 2; t++) {
          f32x4 rsum = {};
          #pragma unroll
          for (int kk = 0; kk < 2; kk++) {
            const bf16x8 pf = *(const bf16x8*)&Pl[wave*2 + t][l16][kk*32 + quad*8];
            #pragma unroll
            for (int nf = 0; nf < 4; nf++) {
              const bf16x8 vf = *(const bf16x8*)&Vs[(nf*16 + l16)*64 + kk*32 + quad*8];
              acc[t][nf] = __builtin_amdgcn_mfma_f32_16x16x32_bf16(pf, vf, acc[t][nf], 0, 0, 0);
            }
            rsum = __builtin_amdgcn_mfma_f32_16x16x32_bf16(pf, ones, rsum, 0, 0, 0);
          }
          #pragma unroll
          for (int r = 0; r < 4; r++) lrow[t][r] += rsum[r];
        }
      }
      __syncthreads();
    }

    #pragma unroll
    for (int t = 0; t < 2; t++) {
      #pragma unroll
      for (int r = 0; r < 4; r++) {
        const float inv = 1.0f / lrow[t][r];
        const int trow = qs0 + t*16 + quad*4 + r;
        const size_t off = ((size_t)(b * SEQ + trow)) * D_MODEL + h * HDIM;
        #pragma unroll
        for (int nf = 0; nf < 4; nf++)
          Yb[off + nf*16 + l16] = f2bf(acc[t][nf][r] * inv);
      }
    }
  }
}

extern "C" void kernel_launch(void* const* d_in, const int* in_sizes, int n_in,
                              void* d_out, int out_size, void* d_ws, size_t ws_size,
                              hipStream_t stream) {
  const float* x     = (const float*)d_in[0];
  const float* w_qkv = (const float*)d_in[1];
  const float* b_qkv = (const float*)d_in[2];
  const float* w_out = (const float*)d_in[3];
  const float* b_out = (const float*)d_in[4];
  float* out = (float*)d_out;

  const size_t SZ = (size_t)BATCH * NHEADS * SEQ * HDIM;   // 8M elems
  unsigned short* Qb  = (unsigned short*)d_ws;             // 16 MiB
  unsigned short* Kb  = Qb + SZ;                           // 16 MiB
  unsigned short* Vb  = Kb + SZ;                           // 16 MiB (V^T)
  unsigned short* Xb  = Vb + SZ;                           // 16 MiB, aliased by Yb
  unsigned short* Yb  = Xb;                                // attn writes after gemm0 reads
  unsigned short* WqT = Xb + SZ;                           // 6 MiB
  unsigned short* WoT = WqT + (size_t)3*D_MODEL*D_MODEL;   // 2 MiB

  cast_kernel<<<dim3((BATCH*SEQ*D_MODEL)/(256*8)), 256, 0, stream>>>(x, Xb);
  transpose_cast<<<dim3(3*D_MODEL/64, D_MODEL/64), 256, 0, stream>>>(w_qkv, WqT, 3*D_MODEL);
  transpose_cast<<<dim3(D_MODEL/64, D_MODEL/64), 256, 0, stream>>>(w_out, WoT, D_MODEL);

  gemm8p<0><<<dim3(3*D_MODEL/256, BATCH*SEQ/128), 512, 0, stream>>>(
      Xb, WqT, b_qkv, Qb, Kb, Vb, nullptr);
  attn_kernel<<<dim3(BATCH*NHEADS, 8), 256, 0, stream>>>(Qb, Kb, Vb, Yb);
  gemm8p<1><<<dim3(D_MODEL/256, BATCH*SEQ/128), 512, 0, stream>>>(
      Yb, WoT, b_out, nullptr, nullptr, nullptr, out);
}